// Round 1
// baseline (126.829 us; speedup 1.0000x reference)
//
#include <hip/hip_runtime.h>

#define NCLS 36
#define KSEL 50
#define BATCH 8
#define DIM 32
#define NPIX 65536          // 256*256
#define TEMP_ 0.1f
#define BASE_TEMP_ 0.07f
#define ROWS (NCLS*KSEL)    // 1800
#define BLOCKS_PER_B 29     // ceil(1800/64)

// ---------------------------------------------------------------------------
// Kernel A (fused):
//   blocks [0,256):   seg scatter-reduce, one block per (b,d) plane
//   blocks [256,264): per-b class histogram (counts) + zero loss accumulators
//   blocks [264,552): first-K index selection, one wave per (b,c)
// ---------------------------------------------------------------------------
__global__ __launch_bounds__(256) void kA(const float* __restrict__ emb,
                                          const int* __restrict__ lab,
                                          float* __restrict__ seg_sum,
                                          int* __restrict__ counts,
                                          int* __restrict__ order,
                                          float* __restrict__ loss_num)
{
    // stride 37: bank = (37*t + c) % 32 = (5t + c) % 32; gcd(5,32)=1 -> ~2-way max
    __shared__ float smem[256 * 37];      // 37,888 B
    const int bid = blockIdx.x;
    const int tid = threadIdx.x;

    if (bid < 256) {
        // ---- seg role: plane (b, d) ----
        const int b = bid >> 5, d = bid & 31;
        const float4* __restrict__ src  = (const float4*)(emb + (size_t)(b * DIM + d) * NPIX);
        const int4*   __restrict__ lsrc = (const int4*)(lab + (size_t)b * NPIX);
        float* acc = smem + tid * 37;
        #pragma unroll
        for (int c = 0; c < 37; ++c) acc[c] = 0.f;
        for (int i = 0; i < NPIX / 1024; ++i) {   // 64 iters, 4 px/thread/iter
            const int idx = i * 256 + tid;
            float4 v = src[idx];
            int4   l = lsrc[idx];
            acc[l.x] += v.x; acc[l.y] += v.y; acc[l.z] += v.z; acc[l.w] += v.w;
        }
        __syncthreads();
        if (tid < NCLS) {
            float s = 0.f;
            for (int t = 0; t < 256; ++t) s += smem[t * 37 + tid];
            seg_sum[((size_t)b * NCLS + tid) * DIM + d] = s;
        }
    } else if (bid < 264) {
        // ---- counts role: batch b ----
        const int b = bid - 256;
        int* acc = (int*)smem + tid * 37;
        #pragma unroll
        for (int c = 0; c < 37; ++c) acc[c] = 0;
        const int4* __restrict__ lsrc = (const int4*)(lab + (size_t)b * NPIX);
        for (int i = 0; i < NPIX / 1024; ++i) {
            int4 l = lsrc[i * 256 + tid];
            acc[l.x]++; acc[l.y]++; acc[l.z]++; acc[l.w]++;
        }
        __syncthreads();
        if (tid < NCLS) {
            int s = 0;
            for (int t = 0; t < 256; ++t) s += ((int*)smem)[t * 37 + tid];
            counts[b * NCLS + tid] = s;
        }
        if (b == 0 && tid < BATCH) loss_num[tid] = 0.f;  // zero accumulators (ws is poisoned)
    } else {
        // ---- topk role: one wave per (b,c), ordered ballot compaction ----
        const int idx = bid - 264;
        const int b = idx / NCLS, c = idx % NCLS;
        if (tid < 64) {
            const int* __restrict__ lb = lab + (size_t)b * NPIX;
            int* __restrict__ dst = order + ((size_t)b * NCLS + c) * KSEL;
            int found = 0;
            for (int n0 = 0; n0 < NPIX && found < KSEL; n0 += 64) {
                const int n = n0 + tid;
                const int match = (lb[n] == c);
                const unsigned long long m = __ballot(match);
                if (match) {
                    const int r = found + __popcll(m & ((1ull << tid) - 1ull));
                    if (r < KSEL) dst[r] = n;
                }
                found += __popcll(m);
            }
        }
    }
}

// ---------------------------------------------------------------------------
// Kernel B: per-row contrastive CE. One thread per row p = c_row*K + k.
// ---------------------------------------------------------------------------
__global__ __launch_bounds__(64) void kB(const float* __restrict__ emb,
                                         const int* __restrict__ counts_g,
                                         const int* __restrict__ order_g,
                                         const float* __restrict__ seg_sum,
                                         float* __restrict__ loss_num)
{
    __shared__ float seg[NCLS * DIM];   // normalized per-class means (4.6 KB)
    __shared__ int   cnt[NCLS];
    const int b = blockIdx.x / BLOCKS_PER_B;
    const int chunk = blockIdx.x % BLOCKS_PER_B;
    const int tid = threadIdx.x;

    if (tid < NCLS) cnt[tid] = counts_g[b * NCLS + tid];
    __syncthreads();
    for (int i = tid; i < NCLS * DIM; i += 64) {
        const float cn = (float)max(cnt[i >> 5], 1);
        seg[i] = seg_sum[(size_t)b * NCLS * DIM + i] / cn;
    }
    __syncthreads();

    const int p = chunk * 64 + tid;
    float loss = 0.f;
    if (p < ROWS) {
        const int crow = p / KSEL;
        const int k = p - crow * KSEL;
        if (k < cnt[crow]) {                       // pix_valid; else contributes 0
            const int n = order_g[((size_t)b * NCLS + crow) * KSEL + k];
            float f[DIM];
            const float* __restrict__ eb = emb + (size_t)b * DIM * NPIX + n;
            #pragma unroll
            for (int d = 0; d < DIM; ++d) f[d] = eb[(size_t)d * NPIX];

            // online softmax over valid classes (count>0); track own-class logit
            float m = -1e30f, s = 0.f, lrow = 0.f;
            for (int c = 0; c < NCLS; ++c) {
                if (cnt[c] > 0) {                  // block-uniform branch
                    float acc = 0.f;
                    const float4* sp = (const float4*)(seg + c * DIM);
                    #pragma unroll
                    for (int q = 0; q < 8; ++q) {
                        float4 sv = sp[q];
                        acc += f[q*4+0]*sv.x + f[q*4+1]*sv.y
                             + f[q*4+2]*sv.z + f[q*4+3]*sv.w;
                    }
                    const float l = acc * (1.0f / TEMP_);
                    if (c == crow) lrow = l;
                    const float nm = fmaxf(m, l);
                    s = s * expf(m - nm) + expf(l - nm);
                    m = nm;
                }
            }
            loss = -(TEMP_ / BASE_TEMP_) * (lrow - m - logf(s));
        }
    }
    // wave reduction (64 lanes)
    #pragma unroll
    for (int o = 32; o > 0; o >>= 1) loss += __shfl_down(loss, o);
    if (tid == 0) atomicAdd(&loss_num[b], loss);
}

// ---------------------------------------------------------------------------
// Kernel C: finalize. den[b] = sum_c min(count, K); out = mean_b num/den.
// ---------------------------------------------------------------------------
__global__ void kC(const float* __restrict__ loss_num,
                   const int* __restrict__ counts,
                   float* __restrict__ out)
{
    if (blockIdx.x == 0 && threadIdx.x == 0) {
        float total = 0.f;
        for (int b = 0; b < BATCH; ++b) {
            int den = 0;
            for (int c = 0; c < NCLS; ++c) den += min(counts[b * NCLS + c], KSEL);
            total += loss_num[b] / (float)max(den, 1);
        }
        out[0] = total / (float)BATCH;
    }
}

extern "C" void kernel_launch(void* const* d_in, const int* in_sizes, int n_in,
                              void* d_out, int out_size, void* d_ws, size_t ws_size,
                              hipStream_t stream)
{
    const float* emb = (const float*)d_in[0];
    const int*   lab = (const int*)d_in[1];

    float* seg_sum  = (float*)d_ws;                        // B*C*D   = 9216 f
    int*   counts   = (int*)(seg_sum + BATCH * NCLS * DIM);// B*C     = 288 i
    int*   order    = counts + BATCH * NCLS;               // B*C*K   = 14400 i
    float* loss_num = (float*)(order + BATCH * NCLS * KSEL);// B      = 8 f
    float* out      = (float*)d_out;

    kA<<<552, 256, 0, stream>>>(emb, lab, seg_sum, counts, order, loss_num);
    kB<<<BATCH * BLOCKS_PER_B, 64, 0, stream>>>(emb, counts, order, seg_sum, loss_num);
    kC<<<1, 1, 0, stream>>>(loss_num, counts, out);
}